// Round 4
// baseline (567.733 us; speedup 1.0000x reference)
//
#include <hip/hip_runtime.h>

#define NG 1024
#define NT 200
#define NS 16
#define NM 4

// Compiler-only fence: stops IR reordering of barrier-free same-wave LDS
// write->read phases (HW DS pipe is in-order per wave).
#define LDS_FENCE() asm volatile("" ::: "memory")

// ---------- double lane-permute helpers (VALU pipe) ----------
template<int CTRL>
__device__ __forceinline__ double dpp_mov_d(double x) {
    const int lo = __double2loint(x), hi = __double2hiint(x);
    const int plo = __builtin_amdgcn_update_dpp(lo, lo, CTRL, 0xF, 0xF, false);
    const int phi = __builtin_amdgcn_update_dpp(hi, hi, CTRL, 0xF, 0xF, false);
    return __hiloint2double(phi, plo);
}
// sum across the 16 lanes of a DPP row (pairwise tree)
__device__ __forceinline__ double row16_allreduce_d(double x) {
    x += dpp_mov_d<0xB1>(x);   // xor1: quad_perm [1,0,3,2]
    x += dpp_mov_d<0x4E>(x);   // xor2: quad_perm [2,3,0,1]
    x += dpp_mov_d<0x141>(x);  // row_half_mirror == xor4 after above
    x += dpp_mov_d<0x140>(x);  // row_mirror == xor8 after above
    return x;
}
// partner across lane^16: permlane16_swap swaps odd rows of op0 with even
// rows of op1; with both = x, partner lives in r[odd_row ? 0 : 1].
__device__ __forceinline__ double partner16_d(double x, int odd) {
#if __has_builtin(__builtin_amdgcn_permlane16_swap)
    const unsigned lo = (unsigned)__double2loint(x), hi = (unsigned)__double2hiint(x);
    auto rl = __builtin_amdgcn_permlane16_swap(lo, lo, false, false);
    auto rh = __builtin_amdgcn_permlane16_swap(hi, hi, false, false);
    return __hiloint2double((int)(odd ? rh[0] : rh[1]),
                            (int)(odd ? rl[0] : rl[1]));
#else
    (void)odd; return __shfl_xor(x, 16, 64);
#endif
}
__device__ __forceinline__ double partner32_d(double x, int up) {
#if __has_builtin(__builtin_amdgcn_permlane32_swap)
    const unsigned lo = (unsigned)__double2loint(x), hi = (unsigned)__double2hiint(x);
    auto rl = __builtin_amdgcn_permlane32_swap(lo, lo, false, false);
    auto rh = __builtin_amdgcn_permlane32_swap(hi, hi, false, false);
    return __hiloint2double((int)(up ? rh[0] : rh[1]),
                            (int)(up ? rl[0] : rl[1]));
#else
    (void)up; return __shfl_xor(x, 32, 64);
#endif
}
// sum over the 4 row-quads (lanes c, c+16, c+32, c+48)
__device__ __forceinline__ double quad_allreduce_d(double x, int q) {
    x += partner16_d(x, q & 1);
    x += partner32_d(x, (q >> 1) & 1);
    return x;
}

__global__ __launch_bounds__(256, 1)
void kalman_kernel(const float* __restrict__ input,      // [G,T,M]
                   const float* __restrict__ Fm,         // [S,S]
                   const float* __restrict__ Qm,         // [S,S]
                   const float* __restrict__ Hm,         // [M,S]
                   const float* __restrict__ Rm,         // [M,M]
                   const float* __restrict__ init_mean,  // [G,S]
                   const float* __restrict__ init_cov,   // [G,S,S]
                   float* __restrict__ out)
{
    const int lane = threadIdx.x & 63;
    const int wid  = threadIdx.x >> 6;
    const int g    = (blockIdx.x << 2) + wid;
    const int c    = lane & 15;   // column index
    const int q    = lane >> 4;   // row-quad: lane owns rows 4q..4q+3 of col c

    // per-wave LDS scratch
    __shared__ __align__(16) float  lds3[4][NS][20];   // fp32 transpose tile
    __shared__ __align__(16) double lds_K[4][NS][4];   // fp64 K rows
    __shared__ __align__(16) double lds_mean[4][NS];   // fp64 mean broadcast

    // ---- constants ----
    // ErX[tp][gs][tt] = E[4q+tp][4*(q^gs)+tt], E = F - I (exact in fp32:
    // off-diag E==F; diagonal F[i][i]~1 -> Sterbenz-exact subtraction)
    float ErX[4][4][4];
    #pragma unroll
    for (int tp = 0; tp < 4; ++tp) {
        #pragma unroll
        for (int gs = 0; gs < 4; ++gs) {
            const float4 v = *(const float4*)(Fm + (4*q + tp)*NS + 4*(q ^ gs));
            ErX[tp][gs][0] = v.x; ErX[tp][gs][1] = v.y;
            ErX[tp][gs][2] = v.z; ErX[tp][gs][3] = v.w;
        }
        ErX[tp][0][tp] -= 1.0f;   // diagonal lives at gs==0, tt==tp
    }
    // Ecq_d[tt] = (double)E[c][4q+tt]
    double Ecq_d[4];
    {
        const float4 v = *(const float4*)(Fm + c*NS + 4*q);
        float fc[4] = {v.x, v.y, v.z, v.w};
        fc[0] -= (c == 4*q+0) ? 1.0f : 0.0f;
        fc[1] -= (c == 4*q+1) ? 1.0f : 0.0f;
        fc[2] -= (c == 4*q+2) ? 1.0f : 0.0f;
        fc[3] -= (c == 4*q+3) ? 1.0f : 0.0f;
        Ecq_d[0]=fc[0]; Ecq_d[1]=fc[1]; Ecq_d[2]=fc[2]; Ecq_d[3]=fc[3];
    }
    double Hq_d[4][4]; // H[m][4q+t]
    #pragma unroll
    for (int m = 0; m < 4; ++m) {
        const float4 v = *(const float4*)(Hm + m*NS + 4*q);
        Hq_d[m][0]=v.x; Hq_d[m][1]=v.y; Hq_d[m][2]=v.z; Hq_d[m][3]=v.w;
    }
    double Hc_d[4];    // H[m][c]
    #pragma unroll
    for (int m = 0; m < 4; ++m) Hc_d[m] = (double)Hm[m*NS + c];
    double Q_d[4];     // Q[4q+t][c]
    #pragma unroll
    for (int tt = 0; tt < 4; ++tt) Q_d[tt] = (double)Qm[(4*q + tt)*NS + c];
    // R lower triangle in fp64
    const double R00=Rm[0],  R10=Rm[4],  R11=Rm[5],  R20=Rm[8],  R21=Rm[9];
    const double R22=Rm[10], R30=Rm[12], R31=Rm[13], R32=Rm[14], R33=Rm[15];

    // ---- state (fp64) ----
    double p_d[4];
    #pragma unroll
    for (int tt = 0; tt < 4; ++tt)
        p_d[tt] = (double)init_cov[g*NS*NS + (4*q + tt)*NS + c];
    double mean_c_d = (double)init_mean[g*NS + c];
    double mean_q_d[4];
    #pragma unroll
    for (int tt = 0; tt < 4; ++tt)
        mean_q_d[tt] = (double)init_mean[g*NS + 4*q + tt];

    // ---- output pointers ----
    float* pMean = out + (size_t)g*NT*NS + c;
    float* pCov  = out + (size_t)NG*NT*NS + (size_t)g*NT*NS*NS + (4*q)*NS + c;
    float* pMM   = out + (size_t)NG*NT*NS + (size_t)NG*NT*NS*NS + (size_t)g*NT*NM;
    float* pMC   = out + (size_t)NG*NT*NS + (size_t)NG*NT*NS*NS + (size_t)NG*NT*NM
                       + (size_t)g*NT*NM*NM;
    const float* pObsBase = input + (size_t)g*NT*NM;

    // depth-2 obs prefetch (16B/step cold HBM reads, ~900cyc latency)
    float4 obs   = *(const float4*)(pObsBase);
    float4 obs_n = *(const float4*)(pObsBase + NM);

    for (int t = 0; t < NT; ++t) {
        const int tpre = (t + 2 < NT) ? (t + 2) : (NT - 1);
        const float4 obs_nn = *(const float4*)(pObsBase + (size_t)tpre*NM);

        // ---- store state prediction for t ----
        if (q == 0) pMean[0] = (float)mean_c_d;
        #pragma unroll
        for (int tt = 0; tt < 4; ++tt) pCov[tt*NS] = (float)p_d[tt];

        // ---- hm[m] = (H mean)[m]  (fp64 quad reduce) ----
        double hm[4];
        #pragma unroll
        for (int m = 0; m < 4; ++m) {
            hm[m] = quad_allreduce_d(Hq_d[m][0]*mean_q_d[0] + Hq_d[m][1]*mean_q_d[1]
                                   + Hq_d[m][2]*mean_q_d[2] + Hq_d[m][3]*mean_q_d[3], q);
        }
        // ---- pht[n] = (H P)[n][c]  (fp64 quad reduce; exact column view) ----
        double pht[4];
        #pragma unroll
        for (int n = 0; n < 4; ++n) {
            pht[n] = quad_allreduce_d(p_d[0]*Hq_d[n][0] + p_d[1]*Hq_d[n][1]
                                    + p_d[2]*Hq_d[n][2] + p_d[3]*Hq_d[n][3], q);
        }

        // ---- S = H P H^T + R : lower triangle, fp64 row16 reduce ----
        const double s00 = row16_allreduce_d(Hc_d[0]*pht[0]) + R00;
        const double s10 = row16_allreduce_d(Hc_d[1]*pht[0]) + R10;
        const double s11 = row16_allreduce_d(Hc_d[1]*pht[1]) + R11;
        const double s20 = row16_allreduce_d(Hc_d[2]*pht[0]) + R20;
        const double s21 = row16_allreduce_d(Hc_d[2]*pht[1]) + R21;
        const double s22 = row16_allreduce_d(Hc_d[2]*pht[2]) + R22;
        const double s30 = row16_allreduce_d(Hc_d[3]*pht[0]) + R30;
        const double s31 = row16_allreduce_d(Hc_d[3]*pht[1]) + R31;
        const double s32 = row16_allreduce_d(Hc_d[3]*pht[2]) + R32;
        const double s33 = row16_allreduce_d(Hc_d[3]*pht[3]) + R33;

        // ---- measurement outputs for t ----
        if (lane == 0) {
            *(float4*)(pMM)      = make_float4((float)hm[0], (float)hm[1],
                                               (float)hm[2], (float)hm[3]);
            *(float4*)(pMC)      = make_float4((float)s00, (float)s10, (float)s20, (float)s30);
            *(float4*)(pMC + 4)  = make_float4((float)s10, (float)s11, (float)s21, (float)s31);
            *(float4*)(pMC + 8)  = make_float4((float)s20, (float)s21, (float)s22, (float)s32);
            *(float4*)(pMC + 12) = make_float4((float)s30, (float)s31, (float)s32, (float)s33);
        }
        pMean += NS; pCov += NS*NS; pMM += NM; pMC += NM*NM;
        if (t == NT-1) break;

        // ---- Cholesky of S (fp64, replicated, branch-free) ----
        const double l00 = sqrt(s00);
        const double i0  = 1.0 / l00;
        const double L10 = s10*i0, L20 = s20*i0, L30 = s30*i0;
        const double l11 = sqrt(s11 - L10*L10);
        const double i1  = 1.0 / l11;
        const double L21 = (s21 - L20*L10)*i1;
        const double L31 = (s31 - L30*L10)*i1;
        const double l22 = sqrt(s22 - L20*L20 - L21*L21);
        const double i2  = 1.0 / l22;
        const double L32 = (s32 - L30*L20 - L31*L21)*i2;
        const double l33 = sqrt(s33 - L30*L30 - L31*L31 - L32*L32);
        const double i3  = 1.0 / l33;

        // ---- K row c: solve S k = pht (fp64) ----
        const double y0 = pht[0]*i0;
        const double y1 = (pht[1] - L10*y0)*i1;
        const double y2 = (pht[2] - L20*y0 - L21*y1)*i2;
        const double y3 = (pht[3] - L30*y0 - L31*y1 - L32*y2)*i3;
        double Kc[4];
        Kc[3] = y3*i3;
        Kc[2] = (y2 - L32*Kc[3])*i2;
        Kc[1] = (y1 - L21*Kc[2] - L31*Kc[3])*i1;
        Kc[0] = (y0 - L10*Kc[1] - L20*Kc[2] - L30*Kc[3])*i0;

        const double r0 = (double)obs.x - hm[0], r1 = (double)obs.y - hm[1],
                     r2 = (double)obs.z - hm[2], r3 = (double)obs.w - hm[3];

        // mean_u[c] via the lane's own K row (c view)
        const double mu_c_d = mean_c_d + Kc[0]*r0 + Kc[1]*r1 + Kc[2]*r2 + Kc[3]*r3;

        // ---- K rows 4q+tt via LDS broadcast (fp64) ----
        if (q == 0) {
            *(double2*)&lds_K[wid][c][0] = make_double2(Kc[0], Kc[1]);
            *(double2*)&lds_K[wid][c][2] = make_double2(Kc[2], Kc[3]);
        }
        LDS_FENCE();
        double Kq[4][4];
        #pragma unroll
        for (int tt = 0; tt < 4; ++tt) {
            const double2 k0 = *(const double2*)&lds_K[wid][4*q + tt][0];
            const double2 k1 = *(const double2*)&lds_K[wid][4*q + tt][2];
            Kq[tt][0]=k0.x; Kq[tt][1]=k0.y; Kq[tt][2]=k1.x; Kq[tt][3]=k1.y;
        }

        // ---- cov_u (fp64) and mean_u (q view, fp64) ----
        double cu_d[4], mu_q_d[4];
        #pragma unroll
        for (int tt = 0; tt < 4; ++tt) {
            cu_d[tt] = p_d[tt] - (Kq[tt][0]*pht[0] + Kq[tt][1]*pht[1]
                                + Kq[tt][2]*pht[2] + Kq[tt][3]*pht[3]);
            mu_q_d[tt] = mean_q_d[tt] + Kq[tt][0]*r0 + Kq[tt][1]*r1
                                      + Kq[tt][2]*r2 + Kq[tt][3]*r3;
        }

        // ---- mean predict: mean_p = mean_u + E*mean_u (fp64) ----
        mean_c_d = mu_c_d + quad_allreduce_d(Ecq_d[0]*mu_q_d[0] + Ecq_d[1]*mu_q_d[1]
                                           + Ecq_d[2]*mu_q_d[2] + Ecq_d[3]*mu_q_d[3], q);
        if (q == 0) lds_mean[wid][c] = mean_c_d;

        // ---- cov predict via E-decomposition:
        //   P+ = cu + W + W^T + (E cu E^T) + Q,  W = E*cu  (corrections fp32;
        //   the dominant cu term stays fp64 -> no per-step storage rounding) ----
        float cu_f[4];
        #pragma unroll
        for (int tt = 0; tt < 4; ++tt) cu_f[tt] = (float)cu_d[tt];
        // Phase A: transposed tile: lds3[a][b] = cu[b][a]
        *(float4*)&lds3[wid][c][4*q] = make_float4(cu_f[0],cu_f[1],cu_f[2],cu_f[3]);
        LDS_FENCE();
        // Phase B: read column c of cu (XOR chunk order matches ErX)
        float col[4][4];
        #pragma unroll
        for (int gs = 0; gs < 4; ++gs) {
            const float4 v = *(const float4*)&lds3[wid][c][4*(q ^ gs)];
            col[gs][0]=v.x; col[gs][1]=v.y; col[gs][2]=v.z; col[gs][3]=v.w;
        }
        // mean_q for next step (read shares fence with Phase A->B)
        {
            const double2 m0 = *(const double2*)&lds_mean[wid][4*q];
            const double2 m1 = *(const double2*)&lds_mean[wid][4*q + 2];
            mean_q_d[0]=m0.x; mean_q_d[1]=m0.y; mean_q_d[2]=m1.x; mean_q_d[3]=m1.y;
        }
        // Phase C: w[tp] = W[4q+tp][c] = sum_k E[4q+tp][k]*cu[k][c]
        float w[4];
        #pragma unroll
        for (int tp = 0; tp < 4; ++tp) {
            float a = 0.0f;
            #pragma unroll
            for (int gs = 0; gs < 4; ++gs)
                #pragma unroll
                for (int tt = 0; tt < 4; ++tt)
                    a += ErX[tp][gs][tt]*col[gs][tt];
            w[tp] = a;
        }
        // Phase D: write W in [row][col] layout
        #pragma unroll
        for (int tp = 0; tp < 4; ++tp) lds3[wid][4*q + tp][c] = w[tp];
        LDS_FENCE();
        // Phase E: read row c of W; gs==0 chunk doubles as W^T elements
        float rv[4][4];
        #pragma unroll
        for (int gs = 0; gs < 4; ++gs) {
            const float4 v = *(const float4*)&lds3[wid][c][4*(q ^ gs)];
            rv[gs][0]=v.x; rv[gs][1]=v.y; rv[gs][2]=v.z; rv[gs][3]=v.w;
        }
        // vv[tp] = (E cu E^T)[4q+tp][c] via symmetry: sum_k E[4q+tp][k]*W[c][k]
        #pragma unroll
        for (int tp = 0; tp < 4; ++tp) {
            float a = 0.0f;
            #pragma unroll
            for (int gs = 0; gs < 4; ++gs)
                #pragma unroll
                for (int tt = 0; tt < 4; ++tt)
                    a += ErX[tp][gs][tt]*rv[gs][tt];
            // P+ = cu + Q + W + W^T + E cu E^T   (fp64 combine)
            p_d[tp] = cu_d[tp] + Q_d[tp]
                    + (double)w[tp] + (double)rv[0][tp] + (double)a;
        }

        // rotate obs pipeline
        obs = obs_n; obs_n = obs_nn;
    }
}

extern "C" void kernel_launch(void* const* d_in, const int* in_sizes, int n_in,
                              void* d_out, int out_size, void* d_ws, size_t ws_size,
                              hipStream_t stream)
{
    const float* input = (const float*)d_in[0];
    const float* F     = (const float*)d_in[1];
    const float* Q     = (const float*)d_in[2];
    const float* H     = (const float*)d_in[3];
    const float* R     = (const float*)d_in[4];
    const float* imean = (const float*)d_in[5];
    const float* icov  = (const float*)d_in[6];

    kalman_kernel<<<NG/4, 256, 0, stream>>>(input, F, Q, H, R, imean, icov,
                                            (float*)d_out);
}